// Round 1
// 30928.894 us; speedup vs baseline: 1.1314x; 1.1314x over previous
//
#include <hip/hip_runtime.h>

// Problem dims
#define Bdim 256
#define Sdim 512
#define Cdim 512
#define Hdim 512
#define NP 16      // batch pipelines (M=16 rows each)
#define NSLICE 16  // N-slice workgroups per pipeline

typedef __attribute__((ext_vector_type(8))) short bfrag;          // 8 bf16 MFMA A/B frag
typedef __attribute__((ext_vector_type(8))) unsigned short u16x8;
typedef __attribute__((ext_vector_type(4))) float f32x4;          // MFMA C/D frag

__device__ __forceinline__ unsigned short f2bf_rne(float f) {
    union { float f; unsigned u; } v; v.f = f;
    return (unsigned short)((v.u + 0x7fffu + ((v.u >> 16) & 1u)) >> 16);
}
__device__ __forceinline__ float sigmoidf_(float x) { return 1.0f / (1.0f + __expf(-x)); }

// ---------------------------------------------------------------------------
// Pack a K x N fp32 weight into bf16 MFMA B-fragment layout:
//   dst[ (n16*(K/32) + kc)*512 + lane*8 + j ] = B[kc*32 + (lane>>4)*8 + j][n16*16 + (lane&15)]
// TRANS=false: src row-major (K,N). K is always 512 here.
template<bool TRANS>
__global__ __launch_bounds__(256) void pack_weight(const float* __restrict__ src,
                                                   unsigned short* __restrict__ dst,
                                                   int K, int N) {
    int tid = blockIdx.x * 256 + threadIdx.x;
    int total = (K >> 5) * (N >> 4) * 64;
    if (tid >= total) return;
    int lane = tid & 63;
    int blk  = tid >> 6;
    int kc   = blk & 15;
    int n16  = blk >> 4;
    int n  = (n16 << 4) + (lane & 15);
    int kb = (kc << 5) + ((lane >> 4) << 3);
    u16x8 v;
#pragma unroll
    for (int j = 0; j < 8; ++j) {
        int k = kb + j;
        float f = TRANS ? src[(size_t)n * K + k] : src[(size_t)k * N + n];
        v[j] = f2bf_rne(f);
    }
    *(u16x8*)(dst + ((size_t)tid << 3)) = v;
}

// ---------------------------------------------------------------------------
// Composed gate weights: C[k][n] = (Wadd ? Wadd[n][k] : 0) + sum_j A[j][k]*Whm[n][j]
// A is (512,512) row-major, Whm is (2048,512) row-major, C is (512,2048) row-major.
__global__ __launch_bounds__(256) void weff_kernel(const float* __restrict__ A,
                                                   const float* __restrict__ Whm,
                                                   const float* __restrict__ Wadd,
                                                   float* __restrict__ C) {
    int n = blockIdx.x;                       // 0..2047
    int k = blockIdx.y * 256 + threadIdx.x;   // 0..511
    const float* wrow = Whm + (size_t)n * 512;
    float acc = 0.f;
#pragma unroll 8
    for (int j = 0; j < 512; ++j) acc += A[(size_t)j * 512 + k] * wrow[j];
    if (Wadd) acc += Wadd[(size_t)n * 512 + k];
    C[(size_t)k * 2048 + n] = acc;
}

// beff[n] = bih[n] + bhm[n] + sum_j (bmx[j]+bmh[j]) * Whm[n][j]
__global__ __launch_bounds__(256) void beff_kernel(const float* __restrict__ bmx,
                                                   const float* __restrict__ bmh,
                                                   const float* __restrict__ Whm,
                                                   const float* __restrict__ bih,
                                                   const float* __restrict__ bhm,
                                                   float* __restrict__ beff) {
    int n = blockIdx.x * 256 + threadIdx.x;
    const float* wrow = Whm + (size_t)n * 512;
    float acc = bih[n] + bhm[n];
#pragma unroll 8
    for (int j = 0; j < 512; ++j) acc += (bmx[j] + bmh[j]) * wrow[j];
    beff[n] = acc;
}

__global__ __launch_bounds__(256) void init_state(unsigned short* __restrict__ Hg,
                                                  unsigned short* __restrict__ Hm,
                                                  int* __restrict__ flags) {
    int tid = blockIdx.x * 256 + threadIdx.x;
    if (tid < NP * NSLICE) flags[tid] = 0;
    for (int i = tid; i < NP * 8192; i += gridDim.x * 256) { Hg[i] = 0; Hm[i] = 0; }
}

// ---------------------------------------------------------------------------
// Persistent-kernel helpers. All cross-WG data goes through AGENT-scope (sc1)
// atomics: stores write through to LIC, loads bypass the (possibly stale)
// per-XCD L2 — correct regardless of XCD placement. No cache-inv fences are
// issued, so weight slices stay L2-resident across all 512 timesteps.

__device__ __forceinline__ bfrag afrag_load(const unsigned short* F, int kc, int lane) {
    union { unsigned long long u[2]; bfrag f; } v;
    const unsigned long long* pp = (const unsigned long long*)(F + kc * 512 + lane * 8);
    v.u[0] = __hip_atomic_load(pp,     __ATOMIC_RELAXED, __HIP_MEMORY_SCOPE_AGENT);
    v.u[1] = __hip_atomic_load(pp + 1, __ATOMIC_RELAXED, __HIP_MEMORY_SCOPE_AGENT);
    return v.f;
}

// Store one (m,n) bf16 output element into A-fragment layout. Lane pairs
// (n even / n odd) are combined via shfl into a single 4B atomic store so we
// never need 16-bit atomics.
__device__ __forceinline__ void store_pair(unsigned short* Dst, int m, int n,
                                           unsigned short b, int lane) {
    unsigned pb = __shfl_xor((unsigned)b, 1);
    if (!(lane & 1)) {
        unsigned word = (unsigned)b | (pb << 16);
        int idx = ((n >> 5) << 9) + (((m & 15) + ((n >> 3) & 3) * 16) << 3) + (n & 7);
        __hip_atomic_store((unsigned*)(Dst + idx), word,
                           __ATOMIC_RELAXED, __HIP_MEMORY_SCOPE_AGENT);
    }
}

// Wait until all 16 slices of this pipeline have completed >= target stages.
__device__ __forceinline__ void wait_flags(const int* fl, int target, int lane) {
    while (true) {
        int f = __hip_atomic_load(fl + (lane & 15), __ATOMIC_RELAXED, __HIP_MEMORY_SCOPE_AGENT);
        if (__all(f >= target)) break;
        __builtin_amdgcn_s_sleep(1);
    }
    asm volatile("" ::: "memory");   // keep the sc1 data loads below the poll
}

// Release: all our sc1 data stores are already headed to LIC; just drain the
// wave's vmem queue, then publish the new stage count.
__device__ __forceinline__ void post_flag(int* fl, int s, int qnew, int lane) {
    asm volatile("s_waitcnt vmcnt(0)" ::: "memory");
    if (lane == 0)
        __hip_atomic_store(fl + s, qnew, __ATOMIC_RELAXED, __HIP_MEMORY_SCOPE_AGENT);
}

// One mogrifier stage for this WG's 32-column slice:
//   new = 2*sigmoid( (A @ W)[:, slice] ) * prev  ; prev/new live in registers,
//   bf16 copy scattered into Dst's A-fragment layout for the next consumers.
__device__ __forceinline__ void mog_stage(const unsigned short* __restrict__ Af,
                                          const unsigned short* __restrict__ Wp,
                                          unsigned short* __restrict__ Dst,
                                          float pv[2][4],
                                          int s, int lane, int lm, int lq) {
    f32x4 acc[2] = {};
    const bfrag* B = (const bfrag*)Wp + (size_t)s * 2048 + lane;  // n16 = s*2 base
#pragma unroll 8
    for (int kc = 0; kc < 16; ++kc) {
        bfrag a = afrag_load(Af, kc, lane);
        acc[0] = __builtin_amdgcn_mfma_f32_16x16x32_bf16(a, B[kc * 64],        acc[0], 0, 0, 0);
        acc[1] = __builtin_amdgcn_mfma_f32_16x16x32_bf16(a, B[1024 + kc * 64], acc[1], 0, 0, 0);
    }
#pragma unroll
    for (int nt = 0; nt < 2; ++nt)
#pragma unroll
        for (int r = 0; r < 4; ++r) {
            int n = s * 32 + nt * 16 + lm;     // C/D: col=lane&15, row=(lane>>4)*4+r
            int m = lq * 4 + r;
            float v = 2.0f * sigmoidf_(acc[nt][r]) * pv[nt][r];
            pv[nt][r] = v;
            store_pair(Dst, m, n, f2bf_rne(v), lane);
        }
}

// ---------------------------------------------------------------------------
// The whole S=512 recurrence in ONE kernel.
// Grid: 256 WGs x 64 thr. WG w: pipeline p = w>>4 (batch rows p*16..p*16+15),
// slice s = w&15 (columns s*32..s*32+31). blockIdx%8 == s%8, so same-slice WGs
// (which share weight slices) land on the same XCD (locality heuristic only).
// Per pipeline, stage completion is tracked by 16 monotonically increasing
// flags; stage q may read its inputs once all flags >= q (this also makes
// every buffer overwrite safe: writers of stage q+1 can only run after all
// stage-q reads are finished).
__global__ __launch_bounds__(64)
void moglstm_persistent(const float* __restrict__ x,
                        const unsigned short* __restrict__ Qp,
                        const unsigned short* __restrict__ Rp,
                        const unsigned short* __restrict__ WXp,
                        const unsigned short* __restrict__ WHp,
                        const float* __restrict__ beff,
                        unsigned short* __restrict__ Xb,
                        unsigned short* __restrict__ Hmb,
                        unsigned short* __restrict__ Hgb,
                        int* __restrict__ flags,
                        float* __restrict__ out) {
    const int w = blockIdx.x;
    const int p = w >> 4, s = w & 15;
    const int lane = threadIdx.x & 63, lm = lane & 15, lq = lane >> 4;
    unsigned short* Xp = Xb + p * 8192;   // x-vector buffer (frag layout)
    unsigned short* Hm = Hmb + p * 8192;  // h1/h2 buffer
    unsigned short* Hg = Hgb + p * 8192;  // gates-output h buffer (h0 next step)
    int* fl = flags + p * NSLICE;

    float px[2][4];                 // this WG's x slice (fp32 master)
    float ph[2][4] = {};            // this WG's h slice
    float cst[2][4] = {};           // cell state slice — registers only
    float bia[4][2];
#pragma unroll
    for (int g = 0; g < 4; ++g)
#pragma unroll
        for (int nt = 0; nt < 2; ++nt)
            bia[g][nt] = beff[g * 512 + s * 32 + nt * 16 + lm];

    const size_t xbase = (size_t)(p * 16) * Sdim * Cdim;
    const size_t obase = (size_t)(p * 16) * Sdim * Hdim;

    int q = 0;
#pragma unroll 1
    for (int t = 0; t < Sdim; ++t) {
        // Preload x_t elementwise BEFORE the poll (independent of flags).
#pragma unroll
        for (int nt = 0; nt < 2; ++nt)
#pragma unroll
            for (int r = 0; r < 4; ++r) {
                int n = s * 32 + nt * 16 + lm;
                int m = lq * 4 + r;
                px[nt][r] = x[xbase + (size_t)m * (Sdim * Cdim) + (size_t)t * Cdim + n];
            }
        // s0: x1 = 2σ(h0@Q)·x_t        (reads Hg, writes X)
        wait_flags(fl, q, lane);
        mog_stage(Hg, Qp, Xp, px, s, lane, lm, lq);
        post_flag(fl, s, ++q, lane);
        // s1: h1 = 2σ(x1@R)·h0         (reads X, writes Hm; h0 in regs)
        wait_flags(fl, q, lane);
        mog_stage(Xp, Rp, Hm, ph, s, lane, lm, lq);
        post_flag(fl, s, ++q, lane);
        // s2: x2 = 2σ(h1@Q)·x1
        wait_flags(fl, q, lane);
        mog_stage(Hm, Qp, Xp, px, s, lane, lm, lq);
        post_flag(fl, s, ++q, lane);
        // s3: h2 = 2σ(x2@R)·h1
        wait_flags(fl, q, lane);
        mog_stage(Xp, Rp, Hm, ph, s, lane, lm, lq);
        post_flag(fl, s, ++q, lane);
        // s4: x3 = 2σ(h2@Q)·x2
        wait_flags(fl, q, lane);
        mog_stage(Hm, Qp, Xp, px, s, lane, lm, lq);
        post_flag(fl, s, ++q, lane);
        // s5: gates = x3@Weff_x + h2@Weff_h + beff ; fused LSTM cell.
        wait_flags(fl, q, lane);
        {
            f32x4 acc[4][2] = {};
#pragma unroll 4
            for (int kc = 0; kc < 16; ++kc) {
                bfrag aX = afrag_load(Xp, kc, lane);
                bfrag aH = afrag_load(Hm, kc, lane);
#pragma unroll
                for (int g = 0; g < 4; ++g) {
                    const bfrag* BX = (const bfrag*)WXp + (size_t)((g * 32 + s * 2) * 16 + kc) * 64 + lane;
                    const bfrag* BH = (const bfrag*)WHp + (size_t)((g * 32 + s * 2) * 16 + kc) * 64 + lane;
                    acc[g][0] = __builtin_amdgcn_mfma_f32_16x16x32_bf16(aX, BX[0],    acc[g][0], 0, 0, 0);
                    acc[g][0] = __builtin_amdgcn_mfma_f32_16x16x32_bf16(aH, BH[0],    acc[g][0], 0, 0, 0);
                    acc[g][1] = __builtin_amdgcn_mfma_f32_16x16x32_bf16(aX, BX[1024], acc[g][1], 0, 0, 0);
                    acc[g][1] = __builtin_amdgcn_mfma_f32_16x16x32_bf16(aH, BH[1024], acc[g][1], 0, 0, 0);
                }
            }
#pragma unroll
            for (int nt = 0; nt < 2; ++nt)
#pragma unroll
                for (int r = 0; r < 4; ++r) {
                    int n = s * 32 + nt * 16 + lm;
                    int m = lq * 4 + r;
                    float ig = sigmoidf_(acc[0][nt][r] + bia[0][nt]);
                    float fg = sigmoidf_(acc[1][nt][r] + bia[1][nt]);
                    float gg = tanhf(acc[2][nt][r] + bia[2][nt]);
                    float og = sigmoidf_(acc[3][nt][r] + bia[3][nt]);
                    float c = fg * cst[nt][r] + ig * gg;
                    cst[nt][r] = c;
                    float h = og * tanhf(c);
                    ph[nt][r] = h;                                  // h0 for next t (own slice)
                    store_pair(Hg, m, n, f2bf_rne(h), lane);        // h0 for other slices
                    out[obase + (size_t)m * (Sdim * Hdim) + (size_t)t * Hdim + n] = h;
                }
        }
        post_flag(fl, s, ++q, lane);
    }
}

// ---------------------------------------------------------------------------
extern "C" void kernel_launch(void* const* d_in, const int* in_sizes, int n_in,
                              void* d_out, int out_size, void* d_ws, size_t ws_size,
                              hipStream_t stream) {
    const float* x     = (const float*)d_in[0];
    const float* Wih_w = (const float*)d_in[1];
    const float* Wih_b = (const float*)d_in[2];
    const float* Wmx_w = (const float*)d_in[3];
    const float* Wmx_b = (const float*)d_in[4];
    const float* Wmh_w = (const float*)d_in[5];
    const float* Wmh_b = (const float*)d_in[6];
    const float* Whm_w = (const float*)d_in[7];
    const float* Whm_b = (const float*)d_in[8];
    const float* Q     = (const float*)d_in[9];
    const float* R     = (const float*)d_in[10];
    float* out = (float*)d_out;

    // workspace layout (~9.8 MB)
    unsigned short* packQ  = (unsigned short*)d_ws;
    unsigned short* packR  = packQ  + 512 * 512;
    unsigned short* packWX = packR  + 512 * 512;    // Weff_x packed (512 x 2048)
    unsigned short* packWH = packWX + 512 * 2048;   // Weff_h packed
    unsigned short* Xb  = packWH + 512 * 2048;      // NP * 8192
    unsigned short* Hmb = Xb  + NP * 8192;
    unsigned short* Hgb = Hmb + NP * 8192;
    float* beff    = (float*)(Hgb + NP * 8192);     // 2048
    float* scratch = beff + 2048;                   // 512*2048 fp32 (reused)
    int* flags     = (int*)(scratch + 512 * 2048);  // NP*NSLICE

    pack_weight<false><<<dim3(128), dim3(256), 0, stream>>>(Q, packQ, 512, 512);
    pack_weight<false><<<dim3(128), dim3(256), 0, stream>>>(R, packR, 512, 512);
    // Weff_x = Wih^T + Wmx^T @ Whm^T  (fp32, then pack to bf16 frag layout)
    weff_kernel<<<dim3(2048, 2), dim3(256), 0, stream>>>(Wmx_w, Whm_w, Wih_w, scratch);
    pack_weight<false><<<dim3(512), dim3(256), 0, stream>>>(scratch, packWX, 512, 2048);
    // Weff_h = Wmh^T @ Whm^T
    weff_kernel<<<dim3(2048, 2), dim3(256), 0, stream>>>(Wmh_w, Whm_w, nullptr, scratch);
    pack_weight<false><<<dim3(512), dim3(256), 0, stream>>>(scratch, packWH, 512, 2048);
    beff_kernel<<<dim3(8), dim3(256), 0, stream>>>(Wmx_b, Wmh_b, Whm_w, Wih_b, Whm_b, beff);
    init_state<<<dim3(128), dim3(256), 0, stream>>>(Hgb, Hmb, flags);

    moglstm_persistent<<<dim3(NP * NSLICE), dim3(64), 0, stream>>>(
        x, packQ, packR, packWX, packWH, beff, Xb, Hmb, Hgb, flags, out);
}